// Round 8
// baseline (294.078 us; speedup 1.0000x reference)
//
#include <hip/hip_runtime.h>
#include <hip/hip_bf16.h>

// CausalSelfAttention on MI355X. fp32 in / fp32 out, bf16 MFMA compute.
// [0] merged cvt pre-pass: {x, w_qkv, w_out} -> bf16 (single launch)
// [1] QKV GEMM: 256x256 tile, BK=64, 8 waves (2x4), double-buffered LDS,
//     counted vmcnt(8) across raw s_barrier (loads in flight over barriers),
//     setprio around MFMA clusters, glds16 staging (linear LDS, m198 config)
// [2] flash attention: 4-wave blocks, 32 q-rows/wave, fused per-kt QK^T+softmax
//     (masked-subtile MFMA skip), 3-way mask classification, exp2 softmax,
//     lsum via ones-MFMA, v_perm V-transpose, rotated K/V prefetch, PV st-skip
// [3] out projection via same 256^2 kernel -> d_out fp32
// B=4 T=2048 C=1024 H=16 Dh=64.

#define D_MODEL 1024
#define N_HEADS 16
#define HEAD_DIM 64
#define SEQ 2048
#define BATCH 4

typedef __attribute__((ext_vector_type(8))) short bf16x8;
typedef __attribute__((ext_vector_type(4))) float f32x4;
typedef unsigned int uint;

__device__ __forceinline__ short f2bf(float f) {
    union { float f; uint i; } c; c.f = f;
    uint x = c.i;
    x += 0x7fffu + ((x >> 16) & 1u);   // RNE
    return (short)(x >> 16);
}
__device__ __forceinline__ uint pack2(float a, float b) {
    return (uint)(unsigned short)f2bf(a) | ((uint)(unsigned short)f2bf(b) << 16);
}
__device__ __forceinline__ uint asu(float f) { union { float f; uint i; } c; c.f = f; return c.i; }
// truncating pack of two f32 -> bf16x2 (single v_perm)
__device__ __forceinline__ uint packtr(float lo, float hi) {
    return __builtin_amdgcn_perm(asu(hi), asu(lo), 0x07060302u);
}

// async global->LDS, 16B per lane; LDS dest = wave-uniform base + lane*16
__device__ __forceinline__ void glds16(const void* g, void* l) {
    __builtin_amdgcn_global_load_lds(
        (const __attribute__((address_space(1))) uint*)g,
        (__attribute__((address_space(3))) uint*)l, 16, 0, 0);
}

// ---------- fp32 -> bf16, 3 sources -> contiguous dst ----------
__global__ __launch_bounds__(256) void cvt3_bf16(const float* __restrict__ s0,
                                                 const float* __restrict__ s1,
                                                 const float* __restrict__ s2,
                                                 short* __restrict__ dst,
                                                 int n0, int n01) {
    int i = blockIdx.x * 256 + threadIdx.x;    // vec4 index
    const float* src;
    int off;
    if (i < n0)       { src = s0; off = i; }
    else if (i < n01) { src = s1; off = i - n0; }
    else              { src = s2; off = i - n01; }
    float4 f = *(const float4*)(src + (size_t)off * 4);
    uint2 o; o.x = pack2(f.x, f.y); o.y = pack2(f.z, f.w);
    *(uint2*)(dst + (size_t)i * 4) = o;
}

// ---------- GEMM 256x256: C[M,N] = A[M,K]@B[N,K]^T + bias ----------
// 512 threads = 8 waves (2 Mrows x 4 Ncols); wave tile 128x64 (8x4 16x16 frags).
// BK=64, LDS 128KB: As/Bs[2][256][64] double-buffered, glds16-direct staging
// (linear layout; lane*16 dest matches row=tid>>3, col=(tid&7)*8).
// Pipeline per K-tile: vmcnt(8) [next tile's 8 loads stay in flight] ->
// s_barrier -> ds_read frags + 2x32 MFMA (setprio) -> s_barrier -> STAGE(t+2).
// MODE 0: fp32 out. MODE 1: bf16 scatter q/k/v [B,H,T,Dh].
template <int MODE>
__global__ __launch_bounds__(512, 2) void gemm256(
    const short* __restrict__ A, const short* __restrict__ B,
    const float* __restrict__ bias, float* __restrict__ Cp,
    int M, int N, int K,
    short* __restrict__ qp, short* __restrict__ kp, short* __restrict__ vp)
{
    __shared__ short As[2][256][64];
    __shared__ short Bs[2][256][64];
    const int tid = threadIdx.x;
    const int lane = tid & 63;
    const int wid = tid >> 6;
    const int wr = wid >> 2, wc = wid & 3;       // 2 x 4 wave grid
    const int quad = lane >> 4, l16 = lane & 15;
    const int rowBase = blockIdx.y * 256;
    const int colBase = blockIdx.x * 256;

    // staging: 4 glds16 per matrix per K-tile; issue i covers rows i*64..i*64+63
    const int srow = tid >> 3;            // 0..63
    const int scol = (tid & 7) * 8;       // shorts
    const short* gA = A + (size_t)(rowBase + srow) * K + scol;
    const short* gB = B + (size_t)(colBase + srow) * K + scol;
    const int ldsrow = wid << 3;          // wave-uniform LDS base row

    f32x4 acc[8][4] = {};
    const int NT = K / 64;

#define STAGE(buf, t)                                                         \
    {                                                                         \
        const int k0_ = (t) * 64;                                             \
        _Pragma("unroll")                                                     \
        for (int i_ = 0; i_ < 4; ++i_)                                        \
            glds16(gA + (size_t)(i_ * 64) * K + k0_,                          \
                   &As[buf][i_ * 64 + ldsrow][0]);                            \
        _Pragma("unroll")                                                     \
        for (int i_ = 0; i_ < 4; ++i_)                                        \
            glds16(gB + (size_t)(i_ * 64) * K + k0_,                          \
                   &Bs[buf][i_ * 64 + ldsrow][0]);                            \
    }

    STAGE(0, 0)
    STAGE(1, 1)
    int cur = 0;

    for (int t = 0; t < NT; ++t) {
        // wait for this tile's 8 loads; next tile's 8 may stay in flight
        if (t + 1 < NT) asm volatile("s_waitcnt vmcnt(8)" ::: "memory");
        else            asm volatile("s_waitcnt vmcnt(0)" ::: "memory");
        __builtin_amdgcn_s_barrier();          // all waves' loads landed
        __builtin_amdgcn_sched_barrier(0);     // pin reads below the barrier

        bf16x8 bfr[4][2];
#pragma unroll
        for (int ni = 0; ni < 4; ++ni)
#pragma unroll
            for (int ks = 0; ks < 2; ++ks)
                bfr[ni][ks] = *(const bf16x8*)&Bs[cur][wc * 64 + ni * 16 + l16][ks * 32 + quad * 8];

#pragma unroll
        for (int half = 0; half < 2; ++half) {
            bf16x8 af[4][2];
#pragma unroll
            for (int mi = 0; mi < 4; ++mi)
#pragma unroll
                for (int ks = 0; ks < 2; ++ks)
                    af[mi][ks] = *(const bf16x8*)&As[cur][wr * 128 + half * 64 + mi * 16 + l16][ks * 32 + quad * 8];
            __builtin_amdgcn_s_setprio(1);
#pragma unroll
            for (int mi = 0; mi < 4; ++mi)
#pragma unroll
                for (int ni = 0; ni < 4; ++ni) {
                    acc[half * 4 + mi][ni] = __builtin_amdgcn_mfma_f32_16x16x32_bf16(
                        af[mi][0], bfr[ni][0], acc[half * 4 + mi][ni], 0, 0, 0);
                    acc[half * 4 + mi][ni] = __builtin_amdgcn_mfma_f32_16x16x32_bf16(
                        af[mi][1], bfr[ni][1], acc[half * 4 + mi][ni], 0, 0, 0);
                }
            __builtin_amdgcn_s_setprio(0);
        }

        __builtin_amdgcn_s_barrier();          // all waves done reading buf cur
        __builtin_amdgcn_sched_barrier(0);     // pin STAGE below the barrier
        if (t + 2 < NT) STAGE(cur, t + 2)      // overwrite freed buffer
        cur ^= 1;
    }
#undef STAGE

    // epilogue: C/D frag layout row=quad*4+reg, col=l16
#pragma unroll
    for (int mi = 0; mi < 8; ++mi) {
#pragma unroll
        for (int ni = 0; ni < 4; ++ni) {
#pragma unroll
            for (int r = 0; r < 4; ++r) {
                int row = rowBase + wr * 128 + mi * 16 + quad * 4 + r;
                int col = colBase + wc * 64 + ni * 16 + l16;
                float v = acc[mi][ni][r] + bias[col];
                if (MODE == 0) {
                    Cp[(size_t)row * N + col] = v;
                } else {
                    int which = col >> 10;          // 0:q 1:k 2:v
                    int h = (col >> 6) & 15;
                    int d = col & 63;
                    int b = row >> 11;
                    int t2 = row & 2047;
                    short* dst = (which == 0) ? qp : (which == 1) ? kp : vp;
                    dst[((((size_t)b * N_HEADS + h) * SEQ) + t2) * HEAD_DIM + d] = f2bf(v);
                }
            }
        }
    }
}

// ---------- flash attention ----------
// grid dim3(B*H=64, 16): qt = 15 - blockIdx.y (LPT: heaviest first).
// block = 256 threads = 4 waves; wave owns 32 q-rows (2 sub-tiles of 16).
// S^T = MFMA(A=K-frag LDS, B=Q-frag regs): lane owns 4 consecutive keys per q.
// lsum = P @ ones via MFMA: denominator lands in same lane/reg as numerator.
// Per-(m,kt): fully-masked -> zero store, NO MFMA; clean -> no mask VALU;
// diagonal -> per-element select. Conditions scalarized via readfirstlane.
__global__ __launch_bounds__(256, 2) void attn_fwd(
    const short* __restrict__ Q, const short* __restrict__ K,
    const short* __restrict__ V, short* __restrict__ O)
{
    __shared__ short Ks[64][72];    // [key][d]
    __shared__ short Vt[64][72];    // [d][key]
    __shared__ short Ps[128][72];   // [q][key] (wave-private 32-row stripes)
    const int tid = threadIdx.x;
    const int wave = tid >> 6, lane = tid & 63;
    const int quad = lane >> 4, l16 = lane & 15;
    const int bh = blockIdx.x;
    const int b = bh >> 4, h = bh & 15;
    const int qt = gridDim.y - 1 - blockIdx.y;   // qt=15 dispatched first (LPT)
    const int qbase = qt * 128;
    const short* Qh = Q + (size_t)bh * SEQ * HEAD_DIM;
    const short* Kh = K + (size_t)bh * SEQ * HEAD_DIM;
    const short* Vh = V + (size_t)bh * SEQ * HEAD_DIM;

    const float C1 = 0.125f * 1.44269504f;   // scale * log2(e)
    const float C2 = 14.4269504f;            // 10 * log2(e)

    // constant bf16 1.0 B-fragment for the row-sum MFMA
    bf16x8 onesf;
#pragma unroll
    for (int e = 0; e < 8; ++e) onesf[e] = (short)0x3F80;

    bf16x8 qf[2][2];                    // [m][st] B-frag: Q[q=l16][k=quad*8+j]
#pragma unroll
    for (int m = 0; m < 2; ++m)
#pragma unroll
        for (int st = 0; st < 2; ++st)
            qf[m][st] = *(const bf16x8*)(Qh + (size_t)(qbase + wave * 32 + m * 16 + l16) * HEAD_DIM + st * 32 + quad * 8);

    f32x4 o[2][4] = {};                 // [m][dtile], rows quad*4+r (= local q)
    f32x4 osum[2] = {};                 // P@1 row-sums, same row layout as o

    const int subw = qbase + wave * 32;                  // wave's first q row
    const int subS = __builtin_amdgcn_readfirstlane(subw);

    const int kr = tid >> 2, kc = (tid & 3) * 16;        // K staging: row, col
    const int vk = (tid & 31) * 2, vd = (tid >> 5) * 8;  // V staging: key pair, d base

    const int ntiles = 2 * qt + 2;
    // preload tile 0
    int4 kv0 = *(const int4*)(Kh + (size_t)kr * HEAD_DIM + kc);
    int4 kv1 = *(const int4*)(Kh + (size_t)kr * HEAD_DIM + kc + 8);
    int4 vv0 = *(const int4*)(Vh + (size_t)vk * HEAD_DIM + vd);
    int4 vv1 = *(const int4*)(Vh + (size_t)(vk + 1) * HEAD_DIM + vd);

    for (int j = 0; j < ntiles; ++j) {
        const int kb = j * 64;
        __syncthreads();                 // prior tile fully consumed
        *(int4*)&Ks[kr][kc] = kv0;
        *(int4*)&Ks[kr][kc + 8] = kv1;
        {   // V transpose: v_perm pack (1 op/word), paired b32 writes
            const uint* pa = (const uint*)&vv0;
            const uint* pb = (const uint*)&vv1;
#pragma unroll
            for (int e = 0; e < 4; ++e) {
                uint lo = __builtin_amdgcn_perm(pb[e], pa[e], 0x05040100u);
                uint hi = __builtin_amdgcn_perm(pb[e], pa[e], 0x07060302u);
                *(uint*)&Vt[vd + 2 * e][vk] = lo;
                *(uint*)&Vt[vd + 2 * e + 1][vk] = hi;
            }
        }
        __syncthreads();

        // rotated prefetch: next tile's K/V loads overlap this tile's compute
        {
            const int kbn = (j + 1 < ntiles) ? kb + 64 : kb;   // clamp (no OOB)
            kv0 = *(const int4*)(Kh + (size_t)(kbn + kr) * HEAD_DIM + kc);
            kv1 = *(const int4*)(Kh + (size_t)(kbn + kr) * HEAD_DIM + kc + 8);
            vv0 = *(const int4*)(Vh + (size_t)(kbn + vk) * HEAD_DIM + vd);
            vv1 = *(const int4*)(Vh + (size_t)(kbn + vk + 1) * HEAD_DIM + vd);
        }

        if (kb > subS + 31) continue;   // whole wave's rows masked for this tile

        // fused per-kt: S^T MFMA + softmax + P store.
        {
            const int prowb = wave * 32 + l16;
#pragma unroll
            for (int kt = 0; kt < 4; ++kt) {
                const int kbkt = kb + kt * 16;      // scalar
                bf16x8 kf0, kf1;
                if (kbkt <= subS + 31) {            // needed by at least one m
                    kf0 = *(const bf16x8*)&Ks[kt * 16 + l16][quad * 8];
                    kf1 = *(const bf16x8*)&Ks[kt * 16 + l16][32 + quad * 8];
                }
#pragma unroll
                for (int m = 0; m < 2; ++m) {
                    const int sub = subS + m * 16;  // scalar
                    uint2 u;
                    if (kbkt > sub + 15) {          // fully masked: skip MFMA too
                        u.x = 0u; u.y = 0u;
                    } else {
                        f32x4 tt = {0.f, 0.f, 0.f, 0.f};
                        tt = __builtin_amdgcn_mfma_f32_16x16x32_bf16(kf0, qf[m][0], tt, 0, 0, 0);
                        tt = __builtin_amdgcn_mfma_f32_16x16x32_bf16(kf1, qf[m][1], tt, 0, 0, 0);
                        float p[4];
                        if (kbkt + 15 <= sub) {     // fully unmasked: no mask VALU
#pragma unroll
                            for (int r = 0; r < 4; ++r)
                                p[r] = __builtin_exp2f(__builtin_fmaf(tt[r], C1, -C2));
                        } else {                    // diagonal subtile
                            const int qrow = sub + l16;
#pragma unroll
                            for (int r = 0; r < 4; ++r) {
                                float a = __builtin_fmaf(tt[r], C1, -C2);
                                if (kbkt + quad * 4 + r > qrow) a = -1e30f;
                                p[r] = __builtin_exp2f(a);
                            }
                        }
                        u.x = packtr(p[0], p[1]); u.y = packtr(p[2], p[3]);
                    }
                    *(uint2*)&Ps[prowb + m * 16][kt * 16 + quad * 4] = u;
                }
            }
        }
        // O += P @ V ; osum += P @ 1 (all intra-wave; st=1 skipped when
        // keys 32-63 are fully masked for this wave's rows)
#pragma unroll
        for (int st = 0; st < 2; ++st) {
            if (st == 1 && kb + 32 > subS + 31) break;
            bf16x8 pf0 = *(const bf16x8*)&Ps[wave * 32 + l16][st * 32 + quad * 8];
            bf16x8 pf1 = *(const bf16x8*)&Ps[wave * 32 + 16 + l16][st * 32 + quad * 8];
            osum[0] = __builtin_amdgcn_mfma_f32_16x16x32_bf16(pf0, onesf, osum[0], 0, 0, 0);
            osum[1] = __builtin_amdgcn_mfma_f32_16x16x32_bf16(pf1, onesf, osum[1], 0, 0, 0);
#pragma unroll
            for (int dt = 0; dt < 4; ++dt) {
                bf16x8 vf = *(const bf16x8*)&Vt[dt * 16 + l16][st * 32 + quad * 8];
                o[0][dt] = __builtin_amdgcn_mfma_f32_16x16x32_bf16(pf0, vf, o[0][dt], 0, 0, 0);
                o[1][dt] = __builtin_amdgcn_mfma_f32_16x16x32_bf16(pf1, vf, o[1][dt], 0, 0, 0);
            }
        }
    }

    // epilogue: per-lane normalize, store
#pragma unroll
    for (int m = 0; m < 2; ++m) {
#pragma unroll
        for (int r = 0; r < 4; ++r) {
            float inv = 1.f / osum[m][r];
            int t = qbase + wave * 32 + m * 16 + quad * 4 + r;
            size_t base = ((size_t)b * SEQ + t) * D_MODEL + h * HEAD_DIM;
#pragma unroll
            for (int dt = 0; dt < 4; ++dt)
                O[base + dt * 16 + l16] = f2bf(o[m][dt][r] * inv);
        }
    }
}

extern "C" void kernel_launch(void* const* d_in, const int* in_sizes, int n_in,
                              void* d_out, int out_size, void* d_ws, size_t ws_size,
                              hipStream_t stream)
{
    const float* x     = (const float*)d_in[0];
    const float* w_qkv = (const float*)d_in[1];
    const float* b_qkv = (const float*)d_in[2];
    const float* w_out = (const float*)d_in[3];
    const float* b_out = (const float*)d_in[4];
    float* out = (float*)d_out;

    const int NX = BATCH * SEQ * D_MODEL;          // 8388608
    const int NWQ = 3 * D_MODEL * D_MODEL;
    const int NWO = D_MODEL * D_MODEL;
    const size_t HE = (size_t)BATCH * N_HEADS * SEQ * HEAD_DIM;

    short* xb    = (short*)d_ws;
    short* wqkvb = xb + NX;
    short* woutb = wqkvb + NWQ;
    short* qp    = woutb + NWO;
    short* kp    = qp + HE;
    short* vp    = kp + HE;
    short* ho    = xb;                   // aliases xb (dead after GEMM1)

    const int M = BATCH * SEQ;  // 8192

    // merged cvt: xb|wqkvb|woutb are contiguous in ws; one launch
    cvt3_bf16<<<(NX + NWQ + NWO) / 1024, 256, 0, stream>>>(
        x, w_qkv, w_out, xb, NX / 4, (NX + NWQ) / 4);

    gemm256<1><<<dim3(3 * D_MODEL / 256, M / 256), 512, 0, stream>>>(
        xb, wqkvb, b_qkv, nullptr, M, 3 * D_MODEL, D_MODEL, qp, kp, vp);

    attn_fwd<<<dim3(BATCH * N_HEADS, SEQ / 128), 256, 0, stream>>>(qp, kp, vp, ho);

    gemm256<0><<<dim3(D_MODEL / 256, M / 256), 512, 0, stream>>>(
        ho, woutb, b_out, out, M, D_MODEL, D_MODEL, nullptr, nullptr, nullptr);
}

// Round 9
// 261.448 us; speedup vs baseline: 1.1248x; 1.1248x over previous
//
#include <hip/hip_runtime.h>
#include <hip/hip_bf16.h>

// CausalSelfAttention on MI355X. fp32 in / fp32 out, bf16 MFMA compute.
// [0] merged cvt pre-pass: {x, w_qkv, w_out} -> bf16 (single launch)
// [1] QKV GEMM: 128^2 m97-style, upgraded to minimal-2-phase: dbuf LDS,
//     STAGE(t+1) issued before compute(t), ONE __syncthreads per K-tile
//     (syncthreads' implicit vmcnt(0) is the drain) -> loads in flight
//     during compute. (256^2 1-blk/CU variant regressed: 535 TF, reverted.)
// [2] flash attention: 4-wave blocks, 32 q-rows/wave, same minimal-2-phase
//     K/V double-buffer (1 barrier/tile), fused per-kt QK^T+softmax
//     (masked-subtile MFMA skip), 3-way mask classification, exp2 softmax,
//     lsum via ones-MFMA, v_perm V-transpose, setprio around PV cluster,
//     PV st-skip, LPT grid (1024 blocks, qt desc)
// [3] out projection via same 128^2 kernel -> d_out fp32
// B=4 T=2048 C=1024 H=16 Dh=64.

#define D_MODEL 1024
#define N_HEADS 16
#define HEAD_DIM 64
#define SEQ 2048
#define BATCH 4

typedef __attribute__((ext_vector_type(8))) short bf16x8;
typedef __attribute__((ext_vector_type(4))) float f32x4;
typedef unsigned int uint;

__device__ __forceinline__ short f2bf(float f) {
    union { float f; uint i; } c; c.f = f;
    uint x = c.i;
    x += 0x7fffu + ((x >> 16) & 1u);   // RNE
    return (short)(x >> 16);
}
__device__ __forceinline__ uint pack2(float a, float b) {
    return (uint)(unsigned short)f2bf(a) | ((uint)(unsigned short)f2bf(b) << 16);
}
__device__ __forceinline__ uint asu(float f) { union { float f; uint i; } c; c.f = f; return c.i; }
// truncating pack of two f32 -> bf16x2 (single v_perm)
__device__ __forceinline__ uint packtr(float lo, float hi) {
    return __builtin_amdgcn_perm(asu(hi), asu(lo), 0x07060302u);
}

// async global->LDS, 16B per lane; LDS dest = wave-uniform base + lane*16
__device__ __forceinline__ void glds16(const void* g, void* l) {
    __builtin_amdgcn_global_load_lds(
        (const __attribute__((address_space(1))) uint*)g,
        (__attribute__((address_space(3))) uint*)l, 16, 0, 0);
}

// ---------- fp32 -> bf16, 3 sources -> contiguous dst ----------
__global__ __launch_bounds__(256) void cvt3_bf16(const float* __restrict__ s0,
                                                 const float* __restrict__ s1,
                                                 const float* __restrict__ s2,
                                                 short* __restrict__ dst,
                                                 int n0, int n01) {
    int i = blockIdx.x * 256 + threadIdx.x;    // vec4 index
    const float* src;
    int off;
    if (i < n0)       { src = s0; off = i; }
    else if (i < n01) { src = s1; off = i - n0; }
    else              { src = s2; off = i - n01; }
    float4 f = *(const float4*)(src + (size_t)off * 4);
    uint2 o; o.x = pack2(f.x, f.y); o.y = pack2(f.z, f.w);
    *(uint2*)(dst + (size_t)i * 4) = o;
}

// ---------- GEMM: C[M,N] = A[M,K]@B[N,K]^T + bias ----------
// bf16 A,B via glds16, minimal-2-phase: double-buffered LDS, STAGE(t+1)
// before compute(t), one __syncthreads per tile (drains vmcnt -> buf t+1
// ready at next iter; buf being staged != buf being read; rewrite of a buf
// is two iters later, separated by a barrier).
// MODE 0: fp32 out. MODE 1: bf16 scatter q/k/v [B,H,T,Dh].
template <int MODE>
__global__ __launch_bounds__(256, 2) void gemm_bt(
    const short* __restrict__ A, const short* __restrict__ B,
    const float* __restrict__ bias, float* __restrict__ Cp,
    int M, int N, int K,
    short* __restrict__ qp, short* __restrict__ kp, short* __restrict__ vp)
{
    __shared__ short As[2][128][32];   // unpadded: glds needs contiguous lane*16 dest
    __shared__ short Bs[2][128][32];
    const int tid = threadIdx.x;
    const int wave = tid >> 6, lane = tid & 63;
    const int quad = lane >> 4, l16 = lane & 15;
    const int wm = (wave >> 1) * 64, wn = (wave & 1) * 64;
    const int rowBase = blockIdx.y * 128;
    const int colBase = blockIdx.x * 128;

    const short* gA = A + (size_t)(rowBase + wave * 32 + (lane >> 2)) * K + (lane & 3) * 8;
    const short* gB = B + (size_t)(colBase + wave * 32 + (lane >> 2)) * K + (lane & 3) * 8;

    f32x4 acc[4][4] = {};
    const int NT = K / 32;

#define GSTAGE(buf, k0)                                                \
    {                                                                  \
        glds16(gA + (k0), &As[buf][wave * 32][0]);                     \
        glds16(gA + (size_t)16 * K + (k0), &As[buf][wave * 32 + 16][0]); \
        glds16(gB + (k0), &Bs[buf][wave * 32][0]);                     \
        glds16(gB + (size_t)16 * K + (k0), &Bs[buf][wave * 32 + 16][0]); \
    }

    GSTAGE(0, 0)
    __syncthreads();                       // implicit vmcnt(0): buf0 ready

    for (int t = 0; t < NT; ++t) {
        const int cur = t & 1;
        if (t + 1 < NT) GSTAGE(cur ^ 1, (t + 1) * 32)   // in flight over compute
        bf16x8 af[4], bfr[4];
#pragma unroll
        for (int i = 0; i < 4; ++i)
            af[i] = *(const bf16x8*)&As[cur][wm + i * 16 + l16][quad * 8];
#pragma unroll
        for (int j = 0; j < 4; ++j)
            bfr[j] = *(const bf16x8*)&Bs[cur][wn + j * 16 + l16][quad * 8];
#pragma unroll
        for (int i = 0; i < 4; ++i)
#pragma unroll
            for (int j = 0; j < 4; ++j)
                acc[i][j] = __builtin_amdgcn_mfma_f32_16x16x32_bf16(af[i], bfr[j], acc[i][j], 0, 0, 0);
        __syncthreads();                   // drain staging loads + rendezvous
    }
#undef GSTAGE

#pragma unroll
    for (int i = 0; i < 4; ++i) {
#pragma unroll
        for (int j = 0; j < 4; ++j) {
#pragma unroll
            for (int r = 0; r < 4; ++r) {
                int row = rowBase + wm + i * 16 + quad * 4 + r;   // C/D: row=quad*4+reg
                int col = colBase + wn + j * 16 + l16;            //       col=lane&15
                float v = acc[i][j][r] + bias[col];
                if (MODE == 0) {
                    Cp[(size_t)row * N + col] = v;
                } else {
                    int which = col >> 10;          // 0:q 1:k 2:v
                    int h = (col >> 6) & 15;
                    int d = col & 63;
                    int b = row >> 11;
                    int t2 = row & 2047;
                    short* dst = (which == 0) ? qp : (which == 1) ? kp : vp;
                    dst[((((size_t)b * N_HEADS + h) * SEQ) + t2) * HEAD_DIM + d] = f2bf(v);
                }
            }
        }
    }
}

// ---------- flash attention ----------
// grid dim3(B*H=64, 16): qt = 15 - blockIdx.y (LPT: heaviest first).
// block = 256 threads = 4 waves; wave owns 32 q-rows (2 sub-tiles of 16).
// Minimal-2-phase K/V staging: double-buffered Ks/Vt, write tile j to buf j&1
// + prefetch regs for j+1 BEFORE the single __syncthreads, compute after.
// (Buf p rewritten at iter j+2, after iter j+1's barrier -> race-free; the
// masked 'continue' sits after the barrier so barrier counts match.)
// S^T = MFMA(A=K-frag LDS, B=Q-frag regs); lsum = P @ ones via MFMA.
// Per-(m,kt): fully-masked -> zero store, NO MFMA; clean -> no mask VALU;
// diagonal -> per-element select. Conditions scalarized via readfirstlane.
__global__ __launch_bounds__(256, 2) void attn_fwd(
    const short* __restrict__ Q, const short* __restrict__ K,
    const short* __restrict__ V, short* __restrict__ O)
{
    __shared__ short Ks[2][64][72];    // [buf][key][d]
    __shared__ short Vt[2][64][72];    // [buf][d][key]
    __shared__ short Ps[128][72];      // [q][key] (wave-private 32-row stripes)
    const int tid = threadIdx.x;
    const int wave = tid >> 6, lane = tid & 63;
    const int quad = lane >> 4, l16 = lane & 15;
    const int bh = blockIdx.x;
    const int b = bh >> 4, h = bh & 15;
    const int qt = gridDim.y - 1 - blockIdx.y;   // qt=15 dispatched first (LPT)
    const int qbase = qt * 128;
    const short* Qh = Q + (size_t)bh * SEQ * HEAD_DIM;
    const short* Kh = K + (size_t)bh * SEQ * HEAD_DIM;
    const short* Vh = V + (size_t)bh * SEQ * HEAD_DIM;

    const float C1 = 0.125f * 1.44269504f;   // scale * log2(e)
    const float C2 = 14.4269504f;            // 10 * log2(e)

    // constant bf16 1.0 B-fragment for the row-sum MFMA
    bf16x8 onesf;
#pragma unroll
    for (int e = 0; e < 8; ++e) onesf[e] = (short)0x3F80;

    bf16x8 qf[2][2];                    // [m][st] B-frag: Q[q=l16][k=quad*8+j]
#pragma unroll
    for (int m = 0; m < 2; ++m)
#pragma unroll
        for (int st = 0; st < 2; ++st)
            qf[m][st] = *(const bf16x8*)(Qh + (size_t)(qbase + wave * 32 + m * 16 + l16) * HEAD_DIM + st * 32 + quad * 8);

    f32x4 o[2][4] = {};                 // [m][dtile], rows quad*4+r (= local q)
    f32x4 osum[2] = {};                 // P@1 row-sums, same row layout as o

    const int subw = qbase + wave * 32;                  // wave's first q row
    const int subS = __builtin_amdgcn_readfirstlane(subw);

    const int kr = tid >> 2, kc = (tid & 3) * 16;        // K staging: row, col
    const int vk = (tid & 31) * 2, vd = (tid >> 5) * 8;  // V staging: key pair, d base

    const int ntiles = 2 * qt + 2;
    // preload tile 0
    int4 kv0 = *(const int4*)(Kh + (size_t)kr * HEAD_DIM + kc);
    int4 kv1 = *(const int4*)(Kh + (size_t)kr * HEAD_DIM + kc + 8);
    int4 vv0 = *(const int4*)(Vh + (size_t)vk * HEAD_DIM + vd);
    int4 vv1 = *(const int4*)(Vh + (size_t)(vk + 1) * HEAD_DIM + vd);

    for (int j = 0; j < ntiles; ++j) {
        const int kb = j * 64;
        const int p = j & 1;
        // write tile j into buf p (regs from prev iter's prefetch)
        *(int4*)&Ks[p][kr][kc] = kv0;
        *(int4*)&Ks[p][kr][kc + 8] = kv1;
        {   // V transpose: v_perm pack (1 op/word), paired b32 writes
            const uint* pa = (const uint*)&vv0;
            const uint* pb = (const uint*)&vv1;
#pragma unroll
            for (int e = 0; e < 4; ++e) {
                uint lo = __builtin_amdgcn_perm(pb[e], pa[e], 0x05040100u);
                uint hi = __builtin_amdgcn_perm(pb[e], pa[e], 0x07060302u);
                *(uint*)&Vt[p][vd + 2 * e][vk] = lo;
                *(uint*)&Vt[p][vd + 2 * e + 1][vk] = hi;
            }
        }
        // prefetch tile j+1 into regs (in flight over barrier + compute)
        if (j + 1 < ntiles) {
            const int kbn = kb + 64;
            kv0 = *(const int4*)(Kh + (size_t)(kbn + kr) * HEAD_DIM + kc);
            kv1 = *(const int4*)(Kh + (size_t)(kbn + kr) * HEAD_DIM + kc + 8);
            vv0 = *(const int4*)(Vh + (size_t)(kbn + vk) * HEAD_DIM + vd);
            vv1 = *(const int4*)(Vh + (size_t)(kbn + vk + 1) * HEAD_DIM + vd);
        }
        __syncthreads();                 // buf p staged; prior buf reads done

        if (kb > subS + 31) continue;   // whole wave's rows masked for this tile

        // fused per-kt: S^T MFMA + softmax + P store.
        // S^T[key][q]: MFMA(A=K-frag, B=Q-frag); row=key=quad*4+r, col=q=l16.
        {
            const int prowb = wave * 32 + l16;
#pragma unroll
            for (int kt = 0; kt < 4; ++kt) {
                const int kbkt = kb + kt * 16;      // scalar
                bf16x8 kf0, kf1;
                if (kbkt <= subS + 31) {            // needed by at least one m
                    kf0 = *(const bf16x8*)&Ks[p][kt * 16 + l16][quad * 8];
                    kf1 = *(const bf16x8*)&Ks[p][kt * 16 + l16][32 + quad * 8];
                }
#pragma unroll
                for (int m = 0; m < 2; ++m) {
                    const int sub = subS + m * 16;  // scalar
                    uint2 u;
                    if (kbkt > sub + 15) {          // fully masked: skip MFMA too
                        u.x = 0u; u.y = 0u;
                    } else {
                        f32x4 tt = {0.f, 0.f, 0.f, 0.f};
                        tt = __builtin_amdgcn_mfma_f32_16x16x32_bf16(kf0, qf[m][0], tt, 0, 0, 0);
                        tt = __builtin_amdgcn_mfma_f32_16x16x32_bf16(kf1, qf[m][1], tt, 0, 0, 0);
                        float pp[4];
                        if (kbkt + 15 <= sub) {     // fully unmasked: no mask VALU
#pragma unroll
                            for (int r = 0; r < 4; ++r)
                                pp[r] = __builtin_exp2f(__builtin_fmaf(tt[r], C1, -C2));
                        } else {                    // diagonal subtile
                            const int qrow = sub + l16;
#pragma unroll
                            for (int r = 0; r < 4; ++r) {
                                float a = __builtin_fmaf(tt[r], C1, -C2);
                                if (kbkt + quad * 4 + r > qrow) a = -1e30f;
                                pp[r] = __builtin_exp2f(a);
                            }
                        }
                        u.x = packtr(pp[0], pp[1]); u.y = packtr(pp[2], pp[3]);
                    }
                    *(uint2*)&Ps[prowb + m * 16][kt * 16 + quad * 4] = u;
                }
            }
        }
        // O += P @ V ; osum += P @ 1 (all intra-wave; st=1 skipped when
        // keys 32-63 are fully masked for this wave's rows)
#pragma unroll
        for (int st = 0; st < 2; ++st) {
            if (st == 1 && kb + 32 > subS + 31) break;
            bf16x8 pf0 = *(const bf16x8*)&Ps[wave * 32 + l16][st * 32 + quad * 8];
            bf16x8 pf1 = *(const bf16x8*)&Ps[wave * 32 + 16 + l16][st * 32 + quad * 8];
            __builtin_amdgcn_s_setprio(1);
            osum[0] = __builtin_amdgcn_mfma_f32_16x16x32_bf16(pf0, onesf, osum[0], 0, 0, 0);
            osum[1] = __builtin_amdgcn_mfma_f32_16x16x32_bf16(pf1, onesf, osum[1], 0, 0, 0);
#pragma unroll
            for (int dt = 0; dt < 4; ++dt) {
                bf16x8 vf = *(const bf16x8*)&Vt[p][dt * 16 + l16][st * 32 + quad * 8];
                o[0][dt] = __builtin_amdgcn_mfma_f32_16x16x32_bf16(pf0, vf, o[0][dt], 0, 0, 0);
                o[1][dt] = __builtin_amdgcn_mfma_f32_16x16x32_bf16(pf1, vf, o[1][dt], 0, 0, 0);
            }
            __builtin_amdgcn_s_setprio(0);
        }
    }

    // epilogue: per-lane normalize, store
#pragma unroll
    for (int m = 0; m < 2; ++m) {
#pragma unroll
        for (int r = 0; r < 4; ++r) {
            float inv = 1.f / osum[m][r];
            int t = qbase + wave * 32 + m * 16 + quad * 4 + r;
            size_t base = ((size_t)b * SEQ + t) * D_MODEL + h * HEAD_DIM;
#pragma unroll
            for (int dt = 0; dt < 4; ++dt)
                O[base + dt * 16 + l16] = f2bf(o[m][dt][r] * inv);
        }
    }
}

extern "C" void kernel_launch(void* const* d_in, const int* in_sizes, int n_in,
                              void* d_out, int out_size, void* d_ws, size_t ws_size,
                              hipStream_t stream)
{
    const float* x     = (const float*)d_in[0];
    const float* w_qkv = (const float*)d_in[1];
    const float* b_qkv = (const float*)d_in[2];
    const float* w_out = (const float*)d_in[3];
    const float* b_out = (const float*)d_in[4];
    float* out = (float*)d_out;

    const int NX = BATCH * SEQ * D_MODEL;          // 8388608
    const int NWQ = 3 * D_MODEL * D_MODEL;
    const int NWO = D_MODEL * D_MODEL;
    const size_t HE = (size_t)BATCH * N_HEADS * SEQ * HEAD_DIM;

    short* xb    = (short*)d_ws;
    short* wqkvb = xb + NX;
    short* woutb = wqkvb + NWQ;
    short* qp    = woutb + NWO;
    short* kp    = qp + HE;
    short* vp    = kp + HE;
    short* ho    = xb;                   // aliases xb (dead after GEMM1)

    const int M = BATCH * SEQ;  // 8192

    // merged cvt: xb|wqkvb|woutb are contiguous in ws; one launch
    cvt3_bf16<<<(NX + NWQ + NWO) / 1024, 256, 0, stream>>>(
        x, w_qkv, w_out, xb, NX / 4, (NX + NWQ) / 4);

    gemm_bt<1><<<dim3(3 * D_MODEL / 128, M / 128), 256, 0, stream>>>(
        xb, wqkvb, b_qkv, nullptr, M, 3 * D_MODEL, D_MODEL, qp, kp, vp);

    attn_fwd<<<dim3(BATCH * N_HEADS, SEQ / 128), 256, 0, stream>>>(qp, kp, vp, ho);

    gemm_bt<0><<<dim3(D_MODEL / 128, M / 128), 256, 0, stream>>>(
        ho, woutb, b_out, out, M, D_MODEL, D_MODEL, nullptr, nullptr, nullptr);
}

// Round 10
// 252.858 us; speedup vs baseline: 1.1630x; 1.0340x over previous
//
#include <hip/hip_runtime.h>
#include <hip/hip_bf16.h>

// CausalSelfAttention on MI355X. fp32 in / fp32 out, bf16 MFMA compute.
// [0] merged cvt pre-pass: {x, w_qkv, w_out} -> bf16 (single launch)
// [1] QKV GEMM: 128^2 m97-style, minimal-2-phase: dbuf LDS, STAGE(t+1) before
//     compute(t), ONE __syncthreads per K-tile (loads in flight during compute)
// [2] flash attention: 4-wave blocks, 32 q-rows/wave, SINGLE-buffer K/V staging
//     (36.9KB LDS = 4 blocks/CU; dbuf variant's 55.3KB -> 2 blk/CU regressed
//     82 vs 72 us), balanced qt map (per-CU-class work equalized: classes
//     {15-y0, 8+y0, 7-y0, y0} each sum 30 qt-units), fused per-kt QK^T+softmax
//     (masked-subtile MFMA skip), 3-way mask classification, exp2 softmax,
//     lsum via ones-MFMA, v_perm V-transpose, rotated K/V prefetch,
//     setprio around PV cluster, PV st-skip
// [3] out projection via same 128^2 kernel -> d_out fp32
// B=4 T=2048 C=1024 H=16 Dh=64.

#define D_MODEL 1024
#define N_HEADS 16
#define HEAD_DIM 64
#define SEQ 2048
#define BATCH 4

typedef __attribute__((ext_vector_type(8))) short bf16x8;
typedef __attribute__((ext_vector_type(4))) float f32x4;
typedef unsigned int uint;

__device__ __forceinline__ short f2bf(float f) {
    union { float f; uint i; } c; c.f = f;
    uint x = c.i;
    x += 0x7fffu + ((x >> 16) & 1u);   // RNE
    return (short)(x >> 16);
}
__device__ __forceinline__ uint pack2(float a, float b) {
    return (uint)(unsigned short)f2bf(a) | ((uint)(unsigned short)f2bf(b) << 16);
}
__device__ __forceinline__ uint asu(float f) { union { float f; uint i; } c; c.f = f; return c.i; }
// truncating pack of two f32 -> bf16x2 (single v_perm)
__device__ __forceinline__ uint packtr(float lo, float hi) {
    return __builtin_amdgcn_perm(asu(hi), asu(lo), 0x07060302u);
}

// async global->LDS, 16B per lane; LDS dest = wave-uniform base + lane*16
__device__ __forceinline__ void glds16(const void* g, void* l) {
    __builtin_amdgcn_global_load_lds(
        (const __attribute__((address_space(1))) uint*)g,
        (__attribute__((address_space(3))) uint*)l, 16, 0, 0);
}

// ---------- fp32 -> bf16, 3 sources -> contiguous dst ----------
__global__ __launch_bounds__(256) void cvt3_bf16(const float* __restrict__ s0,
                                                 const float* __restrict__ s1,
                                                 const float* __restrict__ s2,
                                                 short* __restrict__ dst,
                                                 int n0, int n01) {
    int i = blockIdx.x * 256 + threadIdx.x;    // vec4 index
    const float* src;
    int off;
    if (i < n0)       { src = s0; off = i; }
    else if (i < n01) { src = s1; off = i - n0; }
    else              { src = s2; off = i - n01; }
    float4 f = *(const float4*)(src + (size_t)off * 4);
    uint2 o; o.x = pack2(f.x, f.y); o.y = pack2(f.z, f.w);
    *(uint2*)(dst + (size_t)i * 4) = o;
}

// ---------- GEMM: C[M,N] = A[M,K]@B[N,K]^T + bias ----------
// bf16 A,B via glds16, minimal-2-phase: double-buffered LDS, STAGE(t+1)
// before compute(t), one __syncthreads per tile.
// MODE 0: fp32 out. MODE 1: bf16 scatter q/k/v [B,H,T,Dh].
template <int MODE>
__global__ __launch_bounds__(256, 2) void gemm_bt(
    const short* __restrict__ A, const short* __restrict__ B,
    const float* __restrict__ bias, float* __restrict__ Cp,
    int M, int N, int K,
    short* __restrict__ qp, short* __restrict__ kp, short* __restrict__ vp)
{
    __shared__ short As[2][128][32];   // unpadded: glds needs contiguous lane*16 dest
    __shared__ short Bs[2][128][32];
    const int tid = threadIdx.x;
    const int wave = tid >> 6, lane = tid & 63;
    const int quad = lane >> 4, l16 = lane & 15;
    const int wm = (wave >> 1) * 64, wn = (wave & 1) * 64;
    const int rowBase = blockIdx.y * 128;
    const int colBase = blockIdx.x * 128;

    const short* gA = A + (size_t)(rowBase + wave * 32 + (lane >> 2)) * K + (lane & 3) * 8;
    const short* gB = B + (size_t)(colBase + wave * 32 + (lane >> 2)) * K + (lane & 3) * 8;

    f32x4 acc[4][4] = {};
    const int NT = K / 32;

#define GSTAGE(buf, k0)                                                \
    {                                                                  \
        glds16(gA + (k0), &As[buf][wave * 32][0]);                     \
        glds16(gA + (size_t)16 * K + (k0), &As[buf][wave * 32 + 16][0]); \
        glds16(gB + (k0), &Bs[buf][wave * 32][0]);                     \
        glds16(gB + (size_t)16 * K + (k0), &Bs[buf][wave * 32 + 16][0]); \
    }

    GSTAGE(0, 0)
    __syncthreads();                       // implicit vmcnt(0): buf0 ready

    for (int t = 0; t < NT; ++t) {
        const int cur = t & 1;
        if (t + 1 < NT) GSTAGE(cur ^ 1, (t + 1) * 32)   // in flight over compute
        bf16x8 af[4], bfr[4];
#pragma unroll
        for (int i = 0; i < 4; ++i)
            af[i] = *(const bf16x8*)&As[cur][wm + i * 16 + l16][quad * 8];
#pragma unroll
        for (int j = 0; j < 4; ++j)
            bfr[j] = *(const bf16x8*)&Bs[cur][wn + j * 16 + l16][quad * 8];
#pragma unroll
        for (int i = 0; i < 4; ++i)
#pragma unroll
            for (int j = 0; j < 4; ++j)
                acc[i][j] = __builtin_amdgcn_mfma_f32_16x16x32_bf16(af[i], bfr[j], acc[i][j], 0, 0, 0);
        __syncthreads();                   // drain staging loads + rendezvous
    }
#undef GSTAGE

#pragma unroll
    for (int i = 0; i < 4; ++i) {
#pragma unroll
        for (int j = 0; j < 4; ++j) {
#pragma unroll
            for (int r = 0; r < 4; ++r) {
                int row = rowBase + wm + i * 16 + quad * 4 + r;   // C/D: row=quad*4+reg
                int col = colBase + wn + j * 16 + l16;            //       col=lane&15
                float v = acc[i][j][r] + bias[col];
                if (MODE == 0) {
                    Cp[(size_t)row * N + col] = v;
                } else {
                    int which = col >> 10;          // 0:q 1:k 2:v
                    int h = (col >> 6) & 15;
                    int d = col & 63;
                    int b = row >> 11;
                    int t2 = row & 2047;
                    short* dst = (which == 0) ? qp : (which == 1) ? kp : vp;
                    dst[((((size_t)b * N_HEADS + h) * SEQ) + t2) * HEAD_DIM + d] = f2bf(v);
                }
            }
        }
    }
}

// ---------- flash attention ----------
// grid dim3(B*H=64, 16). Balanced qt map: y0=y&3, g=y>>2;
// qt = g==0 ? 15-y0 : g==1 ? 8+y0 : g==2 ? 7-y0 : y0.
// With CU(bid)=bid mod 256 (breadth-first fill), CU class y0 hosts qt values
// {15-y0, 8+y0, 7-y0, y0} -> each class sums to 30 qt-units (68 tiles): flat
// finish (old 15-y map: 80-8*y0, 18% tail). Heaviest groups still first.
// block = 256 threads = 4 waves; wave owns 32 q-rows (2 sub-tiles of 16).
// S^T = MFMA(A=K-frag LDS, B=Q-frag regs); lsum = P @ ones via MFMA.
// Per-(m,kt): fully-masked -> zero store, NO MFMA; clean -> no mask VALU;
// diagonal -> per-element select. Conditions scalarized via readfirstlane.
__global__ __launch_bounds__(256, 2) void attn_fwd(
    const short* __restrict__ Q, const short* __restrict__ K,
    const short* __restrict__ V, short* __restrict__ O)
{
    __shared__ short Ks[64][72];    // [key][d]
    __shared__ short Vt[64][72];    // [d][key]
    __shared__ short Ps[128][72];   // [q][key] (wave-private 32-row stripes)
    const int tid = threadIdx.x;
    const int wave = tid >> 6, lane = tid & 63;
    const int quad = lane >> 4, l16 = lane & 15;
    const int bh = blockIdx.x;
    const int b = bh >> 4, h = bh & 15;
    const int y = blockIdx.y, y0 = y & 3, g = y >> 2;
    const int qt = (g == 0) ? 15 - y0 : (g == 1) ? 8 + y0 : (g == 2) ? 7 - y0 : y0;
    const int qbase = qt * 128;
    const short* Qh = Q + (size_t)bh * SEQ * HEAD_DIM;
    const short* Kh = K + (size_t)bh * SEQ * HEAD_DIM;
    const short* Vh = V + (size_t)bh * SEQ * HEAD_DIM;

    const float C1 = 0.125f * 1.44269504f;   // scale * log2(e)
    const float C2 = 14.4269504f;            // 10 * log2(e)

    // constant bf16 1.0 B-fragment for the row-sum MFMA
    bf16x8 onesf;
#pragma unroll
    for (int e = 0; e < 8; ++e) onesf[e] = (short)0x3F80;

    bf16x8 qf[2][2];                    // [m][st] B-frag: Q[q=l16][k=quad*8+j]
#pragma unroll
    for (int m = 0; m < 2; ++m)
#pragma unroll
        for (int st = 0; st < 2; ++st)
            qf[m][st] = *(const bf16x8*)(Qh + (size_t)(qbase + wave * 32 + m * 16 + l16) * HEAD_DIM + st * 32 + quad * 8);

    f32x4 o[2][4] = {};                 // [m][dtile], rows quad*4+r (= local q)
    f32x4 osum[2] = {};                 // P@1 row-sums, same row layout as o

    const int subw = qbase + wave * 32;                  // wave's first q row
    const int subS = __builtin_amdgcn_readfirstlane(subw);

    const int kr = tid >> 2, kc = (tid & 3) * 16;        // K staging: row, col
    const int vk = (tid & 31) * 2, vd = (tid >> 5) * 8;  // V staging: key pair, d base

    const int ntiles = 2 * qt + 2;
    // preload tile 0
    int4 kv0 = *(const int4*)(Kh + (size_t)kr * HEAD_DIM + kc);
    int4 kv1 = *(const int4*)(Kh + (size_t)kr * HEAD_DIM + kc + 8);
    int4 vv0 = *(const int4*)(Vh + (size_t)vk * HEAD_DIM + vd);
    int4 vv1 = *(const int4*)(Vh + (size_t)(vk + 1) * HEAD_DIM + vd);

    for (int j = 0; j < ntiles; ++j) {
        const int kb = j * 64;
        __syncthreads();                 // prior tile fully consumed
        *(int4*)&Ks[kr][kc] = kv0;
        *(int4*)&Ks[kr][kc + 8] = kv1;
        {   // V transpose: v_perm pack (1 op/word), paired b32 writes
            const uint* pa = (const uint*)&vv0;
            const uint* pb = (const uint*)&vv1;
#pragma unroll
            for (int e = 0; e < 4; ++e) {
                uint lo = __builtin_amdgcn_perm(pb[e], pa[e], 0x05040100u);
                uint hi = __builtin_amdgcn_perm(pb[e], pa[e], 0x07060302u);
                *(uint*)&Vt[vd + 2 * e][vk] = lo;
                *(uint*)&Vt[vd + 2 * e + 1][vk] = hi;
            }
        }
        __syncthreads();

        // rotated prefetch: next tile's K/V loads overlap this tile's compute
        if (j + 1 < ntiles) {
            const int kbn = kb + 64;
            kv0 = *(const int4*)(Kh + (size_t)(kbn + kr) * HEAD_DIM + kc);
            kv1 = *(const int4*)(Kh + (size_t)(kbn + kr) * HEAD_DIM + kc + 8);
            vv0 = *(const int4*)(Vh + (size_t)(kbn + vk) * HEAD_DIM + vd);
            vv1 = *(const int4*)(Vh + (size_t)(kbn + vk + 1) * HEAD_DIM + vd);
        }

        if (kb > subS + 31) continue;   // whole wave's rows masked for this tile

        // fused per-kt: S^T MFMA + softmax + P store.
        // S^T[key][q]: MFMA(A=K-frag, B=Q-frag); row=key=quad*4+r, col=q=l16.
        {
            const int prowb = wave * 32 + l16;
#pragma unroll
            for (int kt = 0; kt < 4; ++kt) {
                const int kbkt = kb + kt * 16;      // scalar
                bf16x8 kf0, kf1;
                if (kbkt <= subS + 31) {            // needed by at least one m
                    kf0 = *(const bf16x8*)&Ks[kt * 16 + l16][quad * 8];
                    kf1 = *(const bf16x8*)&Ks[kt * 16 + l16][32 + quad * 8];
                }
#pragma unroll
                for (int m = 0; m < 2; ++m) {
                    const int sub = subS + m * 16;  // scalar
                    uint2 u;
                    if (kbkt > sub + 15) {          // fully masked: skip MFMA too
                        u.x = 0u; u.y = 0u;
                    } else {
                        f32x4 tt = {0.f, 0.f, 0.f, 0.f};
                        tt = __builtin_amdgcn_mfma_f32_16x16x32_bf16(kf0, qf[m][0], tt, 0, 0, 0);
                        tt = __builtin_amdgcn_mfma_f32_16x16x32_bf16(kf1, qf[m][1], tt, 0, 0, 0);
                        float p[4];
                        if (kbkt + 15 <= sub) {     // fully unmasked: no mask VALU
#pragma unroll
                            for (int r = 0; r < 4; ++r)
                                p[r] = __builtin_exp2f(__builtin_fmaf(tt[r], C1, -C2));
                        } else {                    // diagonal subtile
                            const int qrow = sub + l16;
#pragma unroll
                            for (int r = 0; r < 4; ++r) {
                                float a = __builtin_fmaf(tt[r], C1, -C2);
                                if (kbkt + quad * 4 + r > qrow) a = -1e30f;
                                p[r] = __builtin_exp2f(a);
                            }
                        }
                        u.x = packtr(p[0], p[1]); u.y = packtr(p[2], p[3]);
                    }
                    *(uint2*)&Ps[prowb + m * 16][kt * 16 + quad * 4] = u;
                }
            }
        }
        // O += P @ V ; osum += P @ 1 (all intra-wave; st=1 skipped when
        // keys 32-63 are fully masked for this wave's rows)
#pragma unroll
        for (int st = 0; st < 2; ++st) {
            if (st == 1 && kb + 32 > subS + 31) break;
            bf16x8 pf0 = *(const bf16x8*)&Ps[wave * 32 + l16][st * 32 + quad * 8];
            bf16x8 pf1 = *(const bf16x8*)&Ps[wave * 32 + 16 + l16][st * 32 + quad * 8];
            __builtin_amdgcn_s_setprio(1);
            osum[0] = __builtin_amdgcn_mfma_f32_16x16x32_bf16(pf0, onesf, osum[0], 0, 0, 0);
            osum[1] = __builtin_amdgcn_mfma_f32_16x16x32_bf16(pf1, onesf, osum[1], 0, 0, 0);
#pragma unroll
            for (int dt = 0; dt < 4; ++dt) {
                bf16x8 vf = *(const bf16x8*)&Vt[dt * 16 + l16][st * 32 + quad * 8];
                o[0][dt] = __builtin_amdgcn_mfma_f32_16x16x32_bf16(pf0, vf, o[0][dt], 0, 0, 0);
                o[1][dt] = __builtin_amdgcn_mfma_f32_16x16x32_bf16(pf1, vf, o[1][dt], 0, 0, 0);
            }
            __builtin_amdgcn_s_setprio(0);
        }
    }

    // epilogue: per-lane normalize, store
#pragma unroll
    for (int m = 0; m < 2; ++m) {
#pragma unroll
        for (int r = 0; r < 4; ++r) {
            float inv = 1.f / osum[m][r];
            int t = qbase + wave * 32 + m * 16 + quad * 4 + r;
            size_t base = ((size_t)b * SEQ + t) * D_MODEL + h * HEAD_DIM;
#pragma unroll
            for (int dt = 0; dt < 4; ++dt)
                O[base + dt * 16 + l16] = f2bf(o[m][dt][r] * inv);
        }
    }
}

extern "C" void kernel_launch(void* const* d_in, const int* in_sizes, int n_in,
                              void* d_out, int out_size, void* d_ws, size_t ws_size,
                              hipStream_t stream)
{
    const float* x     = (const float*)d_in[0];
    const float* w_qkv = (const float*)d_in[1];
    const float* b_qkv = (const float*)d_in[2];
    const float* w_out = (const float*)d_in[3];
    const float* b_out = (const float*)d_in[4];
    float* out = (float*)d_out;

    const int NX = BATCH * SEQ * D_MODEL;          // 8388608
    const int NWQ = 3 * D_MODEL * D_MODEL;
    const int NWO = D_MODEL * D_MODEL;
    const size_t HE = (size_t)BATCH * N_HEADS * SEQ * HEAD_DIM;

    short* xb    = (short*)d_ws;
    short* wqkvb = xb + NX;
    short* woutb = wqkvb + NWQ;
    short* qp    = woutb + NWO;
    short* kp    = qp + HE;
    short* vp    = kp + HE;
    short* ho    = xb;                   // aliases xb (dead after GEMM1)

    const int M = BATCH * SEQ;  // 8192

    // merged cvt: xb|wqkvb|woutb are contiguous in ws; one launch
    cvt3_bf16<<<(NX + NWQ + NWO) / 1024, 256, 0, stream>>>(
        x, w_qkv, w_out, xb, NX / 4, (NX + NWQ) / 4);

    gemm_bt<1><<<dim3(3 * D_MODEL / 128, M / 128), 256, 0, stream>>>(
        xb, wqkvb, b_qkv, nullptr, M, 3 * D_MODEL, D_MODEL, qp, kp, vp);

    attn_fwd<<<dim3(BATCH * N_HEADS, SEQ / 128), 256, 0, stream>>>(qp, kp, vp, ho);

    gemm_bt<0><<<dim3(D_MODEL / 128, M / 128), 256, 0, stream>>>(
        ho, woutb, b_out, out, M, D_MODEL, D_MODEL, nullptr, nullptr, nullptr);
}

// Round 11
// 252.719 us; speedup vs baseline: 1.1637x; 1.0005x over previous
//
#include <hip/hip_runtime.h>
#include <hip/hip_bf16.h>

// CausalSelfAttention on MI355X. fp32 in / fp32 out, bf16 MFMA compute.
// [0] merged cvt pre-pass: {x, w_qkv, w_out} -> bf16 (single launch)
// [1] QKV GEMM: 128^2, counted-vmcnt 2-phase (T4): barrier-first loop,
//     STAGE(t+1) after the barrier, s_waitcnt vmcnt(8) (NOT 0) before frag
//     reads -> next tile's 8 global_load_lds stay in flight across the whole
//     iteration. No vmcnt(0) drain in the main loop (the drain was the m97
//     stall: prior "2-phase" with __syncthreads was semantically 1-phase).
// [2] flash attention: 4-wave blocks, 32 q-rows/wave, single-buffer K/V
//     (4 blk/CU), balanced qt map, fused per-kt QK^T+softmax (masked-subtile
//     MFMA skip), 3-way mask classification, exp2 softmax, lsum via ones-MFMA,
//     v_perm V-transpose, rotated K/V prefetch, setprio PV, PV st-skip
// [3] out projection via same 128^2 kernel -> d_out fp32
// B=4 T=2048 C=1024 H=16 Dh=64.

#define D_MODEL 1024
#define N_HEADS 16
#define HEAD_DIM 64
#define SEQ 2048
#define BATCH 4

typedef __attribute__((ext_vector_type(8))) short bf16x8;
typedef __attribute__((ext_vector_type(4))) float f32x4;
typedef unsigned int uint;

__device__ __forceinline__ short f2bf(float f) {
    union { float f; uint i; } c; c.f = f;
    uint x = c.i;
    x += 0x7fffu + ((x >> 16) & 1u);   // RNE
    return (short)(x >> 16);
}
__device__ __forceinline__ uint pack2(float a, float b) {
    return (uint)(unsigned short)f2bf(a) | ((uint)(unsigned short)f2bf(b) << 16);
}
__device__ __forceinline__ uint asu(float f) { union { float f; uint i; } c; c.f = f; return c.i; }
// truncating pack of two f32 -> bf16x2 (single v_perm)
__device__ __forceinline__ uint packtr(float lo, float hi) {
    return __builtin_amdgcn_perm(asu(hi), asu(lo), 0x07060302u);
}

// async global->LDS, 16B per lane; LDS dest = wave-uniform base + lane*16
__device__ __forceinline__ void glds16(const void* g, void* l) {
    __builtin_amdgcn_global_load_lds(
        (const __attribute__((address_space(1))) uint*)g,
        (__attribute__((address_space(3))) uint*)l, 16, 0, 0);
}

// ---------- fp32 -> bf16, 3 sources -> contiguous dst ----------
__global__ __launch_bounds__(256) void cvt3_bf16(const float* __restrict__ s0,
                                                 const float* __restrict__ s1,
                                                 const float* __restrict__ s2,
                                                 short* __restrict__ dst,
                                                 int n0, int n01) {
    int i = blockIdx.x * 256 + threadIdx.x;    // vec4 index
    const float* src;
    int off;
    if (i < n0)       { src = s0; off = i; }
    else if (i < n01) { src = s1; off = i - n0; }
    else              { src = s2; off = i - n01; }
    float4 f = *(const float4*)(src + (size_t)off * 4);
    uint2 o; o.x = pack2(f.x, f.y); o.y = pack2(f.z, f.w);
    *(uint2*)(dst + (size_t)i * 4) = o;
}

// ---------- GEMM: C[M,N] = A[M,K]@B[N,K]^T + bias ----------
// Counted-vmcnt 2-phase:
//   per tile t: s_barrier (WAR: prior iter's LDS reads done; does NOT drain
//   vmem) -> STAGE(t+1) into freed buf -> s_waitcnt vmcnt(8) (tile t's loads
//   landed; t+1's 8 still in flight) -> ds_read frags -> MFMA.
// Hazards: buf b rewritten at t+1 after the t+1 barrier, last read at t -> safe.
// MODE 0: fp32 out. MODE 1: bf16 scatter q/k/v [B,H,T,Dh].
template <int MODE>
__global__ __launch_bounds__(256, 2) void gemm_bt(
    const short* __restrict__ A, const short* __restrict__ B,
    const float* __restrict__ bias, float* __restrict__ Cp,
    int M, int N, int K,
    short* __restrict__ qp, short* __restrict__ kp, short* __restrict__ vp)
{
    __shared__ short As[2][128][32];   // unpadded: glds needs contiguous lane*16 dest
    __shared__ short Bs[2][128][32];
    const int tid = threadIdx.x;
    const int wave = tid >> 6, lane = tid & 63;
    const int quad = lane >> 4, l16 = lane & 15;
    const int wm = (wave >> 1) * 64, wn = (wave & 1) * 64;
    const int rowBase = blockIdx.y * 128;
    const int colBase = blockIdx.x * 128;

    const short* gA = A + (size_t)(rowBase + wave * 32 + (lane >> 2)) * K + (lane & 3) * 8;
    const short* gB = B + (size_t)(colBase + wave * 32 + (lane >> 2)) * K + (lane & 3) * 8;

    f32x4 acc[4][4] = {};
    const int NT = K / 32;

#define GSTAGE(buf, k0)                                                \
    {                                                                  \
        glds16(gA + (k0), &As[buf][wave * 32][0]);                     \
        glds16(gA + (size_t)16 * K + (k0), &As[buf][wave * 32 + 16][0]); \
        glds16(gB + (k0), &Bs[buf][wave * 32][0]);                     \
        glds16(gB + (size_t)16 * K + (k0), &Bs[buf][wave * 32 + 16][0]); \
    }

    GSTAGE(0, 0)

    for (int t = 0; t < NT; ++t) {
        const int cur = t & 1;
        __builtin_amdgcn_s_barrier();              // WAR rendezvous (no vm drain)
        __builtin_amdgcn_sched_barrier(0);
        if (t + 1 < NT) GSTAGE(cur ^ 1, (t + 1) * 32)   // fly across this iter
        __builtin_amdgcn_sched_barrier(0);
        if (t + 1 < NT) asm volatile("s_waitcnt vmcnt(8)" ::: "memory");
        else            asm volatile("s_waitcnt vmcnt(0)" ::: "memory");
        __builtin_amdgcn_sched_barrier(0);

        bf16x8 af[4], bfr[4];
#pragma unroll
        for (int i = 0; i < 4; ++i)
            af[i] = *(const bf16x8*)&As[cur][wm + i * 16 + l16][quad * 8];
#pragma unroll
        for (int j = 0; j < 4; ++j)
            bfr[j] = *(const bf16x8*)&Bs[cur][wn + j * 16 + l16][quad * 8];
        __builtin_amdgcn_s_setprio(1);
#pragma unroll
        for (int i = 0; i < 4; ++i)
#pragma unroll
            for (int j = 0; j < 4; ++j)
                acc[i][j] = __builtin_amdgcn_mfma_f32_16x16x32_bf16(af[i], bfr[j], acc[i][j], 0, 0, 0);
        __builtin_amdgcn_s_setprio(0);
    }
#undef GSTAGE

#pragma unroll
    for (int i = 0; i < 4; ++i) {
#pragma unroll
        for (int j = 0; j < 4; ++j) {
#pragma unroll
            for (int r = 0; r < 4; ++r) {
                int row = rowBase + wm + i * 16 + quad * 4 + r;   // C/D: row=quad*4+reg
                int col = colBase + wn + j * 16 + l16;            //       col=lane&15
                float v = acc[i][j][r] + bias[col];
                if (MODE == 0) {
                    Cp[(size_t)row * N + col] = v;
                } else {
                    int which = col >> 10;          // 0:q 1:k 2:v
                    int h = (col >> 6) & 15;
                    int d = col & 63;
                    int b = row >> 11;
                    int t2 = row & 2047;
                    short* dst = (which == 0) ? qp : (which == 1) ? kp : vp;
                    dst[((((size_t)b * N_HEADS + h) * SEQ) + t2) * HEAD_DIM + d] = f2bf(v);
                }
            }
        }
    }
}

// ---------- flash attention ----------
// grid dim3(B*H=64, 16). Balanced qt map: y0=y&3, g=y>>2;
// qt = g==0 ? 15-y0 : g==1 ? 8+y0 : g==2 ? 7-y0 : y0 (per-CU-class work equal).
// block = 256 threads = 4 waves; wave owns 32 q-rows (2 sub-tiles of 16).
// S^T = MFMA(A=K-frag LDS, B=Q-frag regs); lsum = P @ ones via MFMA.
// Per-(m,kt): fully-masked -> zero store, NO MFMA; clean -> no mask VALU;
// diagonal -> per-element select. Conditions scalarized via readfirstlane.
__global__ __launch_bounds__(256, 2) void attn_fwd(
    const short* __restrict__ Q, const short* __restrict__ K,
    const short* __restrict__ V, short* __restrict__ O)
{
    __shared__ short Ks[64][72];    // [key][d]
    __shared__ short Vt[64][72];    // [d][key]
    __shared__ short Ps[128][72];   // [q][key] (wave-private 32-row stripes)
    const int tid = threadIdx.x;
    const int wave = tid >> 6, lane = tid & 63;
    const int quad = lane >> 4, l16 = lane & 15;
    const int bh = blockIdx.x;
    const int b = bh >> 4, h = bh & 15;
    const int y = blockIdx.y, y0 = y & 3, g = y >> 2;
    const int qt = (g == 0) ? 15 - y0 : (g == 1) ? 8 + y0 : (g == 2) ? 7 - y0 : y0;
    const int qbase = qt * 128;
    const short* Qh = Q + (size_t)bh * SEQ * HEAD_DIM;
    const short* Kh = K + (size_t)bh * SEQ * HEAD_DIM;
    const short* Vh = V + (size_t)bh * SEQ * HEAD_DIM;

    const float C1 = 0.125f * 1.44269504f;   // scale * log2(e)
    const float C2 = 14.4269504f;            // 10 * log2(e)

    // constant bf16 1.0 B-fragment for the row-sum MFMA
    bf16x8 onesf;
#pragma unroll
    for (int e = 0; e < 8; ++e) onesf[e] = (short)0x3F80;

    bf16x8 qf[2][2];                    // [m][st] B-frag: Q[q=l16][k=quad*8+j]
#pragma unroll
    for (int m = 0; m < 2; ++m)
#pragma unroll
        for (int st = 0; st < 2; ++st)
            qf[m][st] = *(const bf16x8*)(Qh + (size_t)(qbase + wave * 32 + m * 16 + l16) * HEAD_DIM + st * 32 + quad * 8);

    f32x4 o[2][4] = {};                 // [m][dtile], rows quad*4+r (= local q)
    f32x4 osum[2] = {};                 // P@1 row-sums, same row layout as o

    const int subw = qbase + wave * 32;                  // wave's first q row
    const int subS = __builtin_amdgcn_readfirstlane(subw);

    const int kr = tid >> 2, kc = (tid & 3) * 16;        // K staging: row, col
    const int vk = (tid & 31) * 2, vd = (tid >> 5) * 8;  // V staging: key pair, d base

    const int ntiles = 2 * qt + 2;
    // preload tile 0
    int4 kv0 = *(const int4*)(Kh + (size_t)kr * HEAD_DIM + kc);
    int4 kv1 = *(const int4*)(Kh + (size_t)kr * HEAD_DIM + kc + 8);
    int4 vv0 = *(const int4*)(Vh + (size_t)vk * HEAD_DIM + vd);
    int4 vv1 = *(const int4*)(Vh + (size_t)(vk + 1) * HEAD_DIM + vd);

    for (int j = 0; j < ntiles; ++j) {
        const int kb = j * 64;
        __syncthreads();                 // prior tile fully consumed
        *(int4*)&Ks[kr][kc] = kv0;
        *(int4*)&Ks[kr][kc + 8] = kv1;
        {   // V transpose: v_perm pack (1 op/word), paired b32 writes
            const uint* pa = (const uint*)&vv0;
            const uint* pb = (const uint*)&vv1;
#pragma unroll
            for (int e = 0; e < 4; ++e) {
                uint lo = __builtin_amdgcn_perm(pb[e], pa[e], 0x05040100u);
                uint hi = __builtin_amdgcn_perm(pb[e], pa[e], 0x07060302u);
                *(uint*)&Vt[vd + 2 * e][vk] = lo;
                *(uint*)&Vt[vd + 2 * e + 1][vk] = hi;
            }
        }
        __syncthreads();

        // rotated prefetch: next tile's K/V loads overlap this tile's compute
        if (j + 1 < ntiles) {
            const int kbn = kb + 64;
            kv0 = *(const int4*)(Kh + (size_t)(kbn + kr) * HEAD_DIM + kc);
            kv1 = *(const int4*)(Kh + (size_t)(kbn + kr) * HEAD_DIM + kc + 8);
            vv0 = *(const int4*)(Vh + (size_t)(kbn + vk) * HEAD_DIM + vd);
            vv1 = *(const int4*)(Vh + (size_t)(kbn + vk + 1) * HEAD_DIM + vd);
        }

        if (kb > subS + 31) continue;   // whole wave's rows masked for this tile

        // fused per-kt: S^T MFMA + softmax + P store.
        // S^T[key][q]: MFMA(A=K-frag, B=Q-frag); row=key=quad*4+r, col=q=l16.
        {
            const int prowb = wave * 32 + l16;
#pragma unroll
            for (int kt = 0; kt < 4; ++kt) {
                const int kbkt = kb + kt * 16;      // scalar
                bf16x8 kf0, kf1;
                if (kbkt <= subS + 31) {            // needed by at least one m
                    kf0 = *(const bf16x8*)&Ks[kt * 16 + l16][quad * 8];
                    kf1 = *(const bf16x8*)&Ks[kt * 16 + l16][32 + quad * 8];
                }
#pragma unroll
                for (int m = 0; m < 2; ++m) {
                    const int sub = subS + m * 16;  // scalar
                    uint2 u;
                    if (kbkt > sub + 15) {          // fully masked: skip MFMA too
                        u.x = 0u; u.y = 0u;
                    } else {
                        f32x4 tt = {0.f, 0.f, 0.f, 0.f};
                        tt = __builtin_amdgcn_mfma_f32_16x16x32_bf16(kf0, qf[m][0], tt, 0, 0, 0);
                        tt = __builtin_amdgcn_mfma_f32_16x16x32_bf16(kf1, qf[m][1], tt, 0, 0, 0);
                        float p[4];
                        if (kbkt + 15 <= sub) {     // fully unmasked: no mask VALU
#pragma unroll
                            for (int r = 0; r < 4; ++r)
                                p[r] = __builtin_exp2f(__builtin_fmaf(tt[r], C1, -C2));
                        } else {                    // diagonal subtile
                            const int qrow = sub + l16;
#pragma unroll
                            for (int r = 0; r < 4; ++r) {
                                float a = __builtin_fmaf(tt[r], C1, -C2);
                                if (kbkt + quad * 4 + r > qrow) a = -1e30f;
                                p[r] = __builtin_exp2f(a);
                            }
                        }
                        u.x = packtr(p[0], p[1]); u.y = packtr(p[2], p[3]);
                    }
                    *(uint2*)&Ps[prowb + m * 16][kt * 16 + quad * 4] = u;
                }
            }
        }
        // O += P @ V ; osum += P @ 1 (all intra-wave; st=1 skipped when
        // keys 32-63 are fully masked for this wave's rows)
#pragma unroll
        for (int st = 0; st < 2; ++st) {
            if (st == 1 && kb + 32 > subS + 31) break;
            bf16x8 pf0 = *(const bf16x8*)&Ps[wave * 32 + l16][st * 32 + quad * 8];
            bf16x8 pf1 = *(const bf16x8*)&Ps[wave * 32 + 16 + l16][st * 32 + quad * 8];
            __builtin_amdgcn_s_setprio(1);
            osum[0] = __builtin_amdgcn_mfma_f32_16x16x32_bf16(pf0, onesf, osum[0], 0, 0, 0);
            osum[1] = __builtin_amdgcn_mfma_f32_16x16x32_bf16(pf1, onesf, osum[1], 0, 0, 0);
#pragma unroll
            for (int dt = 0; dt < 4; ++dt) {
                bf16x8 vf = *(const bf16x8*)&Vt[dt * 16 + l16][st * 32 + quad * 8];
                o[0][dt] = __builtin_amdgcn_mfma_f32_16x16x32_bf16(pf0, vf, o[0][dt], 0, 0, 0);
                o[1][dt] = __builtin_amdgcn_mfma_f32_16x16x32_bf16(pf1, vf, o[1][dt], 0, 0, 0);
            }
            __builtin_amdgcn_s_setprio(0);
        }
    }

    // epilogue: per-lane normalize, store
#pragma unroll
    for (int m = 0; m < 2; ++m) {
#pragma unroll
        for (int r = 0; r < 4; ++r) {
            float inv = 1.f / osum[m][r];
            int t = qbase + wave * 32 + m * 16 + quad * 4 + r;
            size_t base = ((size_t)b * SEQ + t) * D_MODEL + h * HEAD_DIM;
#pragma unroll
            for (int dt = 0; dt < 4; ++dt)
                O[base + dt * 16 + l16] = f2bf(o[m][dt][r] * inv);
        }
    }
}

extern "C" void kernel_launch(void* const* d_in, const int* in_sizes, int n_in,
                              void* d_out, int out_size, void* d_ws, size_t ws_size,
                              hipStream_t stream)
{
    const float* x     = (const float*)d_in[0];
    const float* w_qkv = (const float*)d_in[1];
    const float* b_qkv = (const float*)d_in[2];
    const float* w_out = (const float*)d_in[3];
    const float* b_out = (const float*)d_in[4];
    float* out = (float*)d_out;

    const int NX = BATCH * SEQ * D_MODEL;          // 8388608
    const int NWQ = 3 * D_MODEL * D_MODEL;
    const int NWO = D_MODEL * D_MODEL;
    const size_t HE = (size_t)BATCH * N_HEADS * SEQ * HEAD_DIM;

    short* xb    = (short*)d_ws;
    short* wqkvb = xb + NX;
    short* woutb = wqkvb + NWQ;
    short* qp    = woutb + NWO;
    short* kp    = qp + HE;
    short* vp    = kp + HE;
    short* ho    = xb;                   // aliases xb (dead after GEMM1)

    const int M = BATCH * SEQ;  // 8192

    // merged cvt: xb|wqkvb|woutb are contiguous in ws; one launch
    cvt3_bf16<<<(NX + NWQ + NWO) / 1024, 256, 0, stream>>>(
        x, w_qkv, w_out, xb, NX / 4, (NX + NWQ) / 4);

    gemm_bt<1><<<dim3(3 * D_MODEL / 128, M / 128), 256, 0, stream>>>(
        xb, wqkvb, b_qkv, nullptr, M, 3 * D_MODEL, D_MODEL, qp, kp, vp);

    attn_fwd<<<dim3(BATCH * N_HEADS, SEQ / 128), 256, 0, stream>>>(qp, kp, vp, ho);

    gemm_bt<0><<<dim3(D_MODEL / 128, M / 128), 256, 0, stream>>>(
        ho, woutb, b_out, out, M, D_MODEL, D_MODEL, nullptr, nullptr, nullptr);
}